// Round 8
// baseline (318.903 us; speedup 1.0000x reference)
//
#include <hip/hip_runtime.h>
#include <stdint.h>

// RandomMaskSubgraphs — round 21: revert to r18 config + occupancy-fixed dedup.
// r20 post-mortem: NB=512 halved dedup waves/CU (54.8KB LDS -> 2 blocks/CU = 8
// waves); dedup 71us, latency-bound (VALU 26%, Occ 19%). ALSO: dedup VGPR=88
// caps at 16 waves/CU (m69: halves at 64/128) — r18's dedup was VGPR-capped too.
// r21 dedup: col-partitioned bitmaps — 4 waves process the SAME row together,
// each owning 1/4 of col space (313 words, 5KB total vs 20KB). Rows sequential
// (40 iters, 1 barrier each; cross-wave offsets via wcnt[40][4], no reuse
// hazard). LDS 37.7->22.3KB -> 7 blocks/CU = 28 waves/CU. Plus
// __launch_bounds__(256,7) to force VGPR <=~72 so VGPR cap doesn't bind.
// Extraction order preserved: wave col-ranges ascending+disjoint.
// k_append/emit: r18 form (NB=1024/RPB=40/CAP=8192/CURSTRIDE=4, APPT=512).
// RULES: no intra-kernel grid sync (r16); no cursor padding (r19); NB=1024 (r20).
// PRNG v0 bit-exact since r4.

#define NN 40000
#define SAMPN (NN / 2)
#define NB 1024                  // buckets (append bins == dedup blocks)
#define RPB 40                   // rows per bucket (1024*40 >= 40000)
#define CAP 8192                 // entries per bucket (mean ~5.3k)
#define CURSTRIDE 4
#define APPT 512                 // k_append threads per block
#define EPB 5632                 // edges per append block (11*512)
#define NE (EPB / APPT)          // 11 edges per thread
#define SELFPB 88                // self nodes per append block (455*88 >= 40000)
#define SCAP (3 * EPB + SELFPB)  // 16984 -> 67.9 KB
#define MWPB 250                 // mask words per extract block (40*250=10000)
#define BMW 313                  // bitmap words per wave (col partition)
#define CSPAN (BMW * 32)         // 10016 cols per wave range

// ---------------- Threefry-2x32 (20 rounds, JAX schedule) ----------------
__host__ __device__ __forceinline__ void tf2x32(unsigned k0, unsigned k1,
                                                unsigned x0, unsigned x1,
                                                unsigned &o0, unsigned &o1) {
  unsigned ks2 = k0 ^ k1 ^ 0x1BD11BDAu;
  x0 += k0; x1 += k1;
#define TFR(r) { x0 += x1; x1 = (x1 << (r)) | (x1 >> (32 - (r))); x1 ^= x0; }
  TFR(13) TFR(15) TFR(26) TFR(6)
  x0 += k1;  x1 += ks2 + 1u;
  TFR(17) TFR(29) TFR(16) TFR(24)
  x0 += ks2; x1 += k0 + 2u;
  TFR(13) TFR(15) TFR(26) TFR(6)
  x0 += k0;  x1 += k1 + 3u;
  TFR(17) TFR(29) TFR(16) TFR(24)
  x0 += k1;  x1 += ks2 + 4u;
  TFR(13) TFR(15) TFR(26) TFR(6)
  x0 += ks2; x1 += k0 + 5u;
#undef TFR
  o0 = x0; o1 = x1;
}

// jax.random.randint element e with pre-split subkeys k1=(a,b), k2=(c,d).
// m2 = ((65536 % span)^2) % span, precomputed by the caller (span-invariant).
__device__ __forceinline__ unsigned jrand(unsigned a, unsigned b, unsigned c,
                                          unsigned d, unsigned e, unsigned span,
                                          unsigned m2) {
  unsigned x0, x1, y0, y1;
  tf2x32(a, b, 0u, e, x0, x1);
  unsigned hi = x0 ^ x1;
  tf2x32(c, d, 0u, e, y0, y1);
  unsigned lo = y0 ^ y1;
  return ((hi % span) * m2 + (lo % span)) % span;
}

// ---------------- init / BFS ----------------
__global__ void k_zero16(uint4 *p, int n16) {
  int i = blockIdx.x * blockDim.x + threadIdx.x;
  if (i < n16) p[i] = make_uint4(0u, 0u, 0u, 0u);
}
__global__ void k_seed_samp(const int *seeds, int ns, unsigned char *cur,
                            unsigned char *mask_bfs,
                            unsigned a, unsigned b, unsigned c, unsigned d) {
  int i = blockIdx.x * blockDim.x + threadIdx.x;
  if (i < ns) { int s = seeds[i]; cur[s] = 1; mask_bfs[s] = 1; }
  if (i < SAMPN) {
    constexpr unsigned M2 =
        ((65536u % (unsigned)NN) * (65536u % (unsigned)NN)) % (unsigned)NN;
    unsigned idx = jrand(a, b, c, d, (unsigned)i, (unsigned)NN, M2);
    mask_bfs[idx] = 1;
  }
}
// level-0 BFS; also zeroes deg + cursors (used by later kernels only).
__global__ void k_level0(const int *rows, const int *cols, int E,
                         const unsigned char *cur, unsigned char *alive,
                         unsigned char *touched, unsigned char *mask_bfs,
                         int *deg, int *cursors) {
  int e = blockIdx.x * blockDim.x + threadIdx.x;
  if (e < NN) deg[e] = 0;
  int e2 = e - NN;
  if (e2 >= 0 && e2 < NB * CURSTRIDE) cursors[e2] = 0;
  if (e >= E) return;
  int r = rows[e], c = cols[e];
  if (cur[r] | cur[c]) {
    alive[e] = 0;
    touched[r] = 1; touched[c] = 1;
    mask_bfs[r] = 1; mask_bfs[c] = 1;
  } else alive[e] = 1;
}
// level-1 BFS + degree; blocks 0..39 also compute mask popcount partials
// (mask_bfs is complete before this kernel launches).
__global__ void k_level1_deg(const int *rows, const int *cols, int E,
                             const unsigned char *touched, unsigned char *alive,
                             int *deg, const unsigned *maskw, int *mask_part) {
  int tid = threadIdx.x;
  int e = blockIdx.x * blockDim.x + tid;
  if (e < E && alive[e]) {
    int r = rows[e];
    if (touched[r] | touched[cols[e]]) alive[e] = 0;
    else atomicAdd(&deg[r], 1);
  }
  if (blockIdx.x < 40) {
    __shared__ int red[4];
    int lane = tid & 63, wid = tid >> 6;
    int c = (tid < MWPB) ? __popc(maskw[blockIdx.x * MWPB + tid]) : 0;
    for (int d = 1; d < 64; d <<= 1) c += __shfl_xor(c, d, 64);
    if (lane == 0) red[wid] = c;
    __syncthreads();
    if (tid == 0) mask_part[blockIdx.x] = red[0] + red[1] + red[2] + red[3];
  }
}

// ---------------- mask extraction (40 blocks; replaces 1-block scan) --------
__global__ __launch_bounds__(256) void k_mask_extract(const unsigned *f,
                                                      const int *mask_part,
                                                      unsigned short *mask_idx,
                                                      int *tem_num) {
  __shared__ int wsum[4];
  __shared__ int basech;
  int b = blockIdx.x, tid = threadIdx.x, lane = tid & 63, wid = tid >> 6;
  if (wid == 0) {
    int v = (lane < 40) ? mask_part[lane] : 0;
    int x = v;
    for (int d = 1; d < 64; d <<= 1) {
      int y = __shfl_up(x, d, 64);
      if (lane >= d) x += y;
    }
    int basev = __shfl(x - v, b, 64);   // exclusive prefix at own block
    int total = __shfl(x, 39, 64);
    if (lane == 0) {
      basech = basev;
      if (b == 0) *tem_num = total;
    }
  }
  int w = b * MWPB + tid;
  unsigned u = (tid < MWPB) ? f[w] : 0u;
  int c = __popc(u);
  int x = c;
  for (int d = 1; d < 64; d <<= 1) {
    int y = __shfl_up(x, d, 64);
    if (lane >= d) x += y;
  }
  if (lane == 63) wsum[wid] = x;
  __syncthreads();
  if (wid == 0) {
    int v = (lane < 4) ? wsum[lane] : 0;
    int y = v;
    for (int d = 1; d < 4; d <<= 1) {
      int z = __shfl_up(y, d, 64);
      if (lane >= d) y += z;
    }
    if (lane < 4) wsum[lane] = y - v;
  }
  __syncthreads();
  int off = basech + wsum[wid] + (x - c);
  while (u) {
    int byte = (__ffs(u) - 1) >> 3;
    u &= u - 1;
    mask_idx[off++] = (unsigned short)(w * 4 + byte);
  }
}

// ---------------- binned append (tem + alive + self) + fused encoder ----------
__global__ __launch_bounds__(APPT) void k_append(
    const int *rows, const int *cols, const unsigned char *alive,
    const int *deg, const unsigned short *mask_idx, const int *tem_num,
    int *cursors, unsigned *bucketmem, float *out,
    unsigned ra, unsigned rb, unsigned rc, unsigned rd,
    unsigned ca, unsigned cb, unsigned cc, unsigned cd, int E) {
  __shared__ unsigned sorted[SCAP];     // 67.9 KB
  __shared__ int cnt[NB];               // 4 KB
  __shared__ unsigned short ofs[NB];    // 2 KB
  __shared__ int ntot_s;
  int tid = threadIdx.x, lane = tid & 63, wid = tid >> 6;
  int e0 = blockIdx.x * EPB;
  int i0 = blockIdx.x * SELFPB;         // self-node range
  int i1 = i0 + SELFPB; if (i1 > NN) i1 = NN;
  unsigned span = (unsigned)*tem_num;
  unsigned mtmp = 65536u % span;
  unsigned m2 = (mtmp * mtmp) % span;   // hoisted out of jrand (span-invariant)
  const unsigned NOPE = 0xFFFFFFFFu;

  unsigned tval[NE], aval[NE];

  for (int i = tid; i < NB; i += APPT) cnt[i] = 0;
  __syncthreads();
  // pass A: draw + gather once, count, cache in registers; fused encoder out
#pragma unroll
  for (int k = 0; k < NE; k++) {
    int e = e0 + k * APPT + tid;
    if (e < E) {
      unsigned iR = jrand(ra, rb, rc, rd, (unsigned)e, span, m2);
      unsigned iC = jrand(ca, cb, cc, cd, (unsigned)e, span, m2);
      unsigned tr = (unsigned)mask_idx[iR], tc = (unsigned)mask_idx[iC];
      tval[k] = (tr << 16) | tc;
      atomicAdd(&cnt[tr / RPB], 1);
      atomicAdd(&cnt[tc / RPB], 1);
      int r = rows[e], c = cols[e];
      float v = 0.0f;
      if (alive[e]) {
        aval[k] = ((unsigned)r << 16) | (unsigned)c;
        atomicAdd(&cnt[(unsigned)r / RPB], 1);
        float xr = (float)deg[r] + 1e-12f;
        float xc = (float)deg[c] + 1e-12f;
        float dr = (float)(1.0 / sqrt((double)xr));
        float dc = (float)(1.0 / sqrt((double)xc));
        v = dr * dc;
      } else aval[k] = NOPE;
      out[e] = (float)r;
      out[E + e] = (float)c;
      out[2 * E + e] = v;
    } else { tval[k] = NOPE; aval[k] = NOPE; }
  }
  for (int i = i0 + tid; i < i1; i += APPT) atomicAdd(&cnt[i / RPB], 1);
  __syncthreads();
  // exclusive scan of cnt[1024] by wave 0 -> ofs (ushort)
  if (wid == 0) {
    int carry = 0;
    for (int c8 = 0; c8 < NB / 64; c8++) {
      int v = cnt[c8 * 64 + lane];
      int x = v;
      for (int d = 1; d < 64; d <<= 1) {
        int y = __shfl_up(x, d, 64);
        if (lane >= d) x += y;
      }
      ofs[c8 * 64 + lane] = (unsigned short)(carry + x - v);
      carry += __shfl(x, 63, 64);
    }
    if (lane == 0) ntot_s = carry;
  }
  __syncthreads();
  for (int i = tid; i < NB; i += APPT) cnt[i] = ofs[i];
  __syncthreads();
  // pass B: scatter from registers (+ self)
#pragma unroll
  for (int k = 0; k < NE; k++) {
    unsigned v = tval[k];
    if (v != NOPE) {
      unsigned tr = v >> 16, tc = v & 0xFFFFu;
      int p1 = atomicAdd(&cnt[tr / RPB], 1);
      sorted[p1] = v;
      int p2 = atomicAdd(&cnt[tc / RPB], 1);
      sorted[p2] = (tc << 16) | tr;
      unsigned a = aval[k];
      if (a != NOPE) {
        int p3 = atomicAdd(&cnt[(a >> 16) / RPB], 1);
        sorted[p3] = a;
      }
    }
  }
  for (int i = i0 + tid; i < i1; i += APPT) {
    int p = atomicAdd(&cnt[i / RPB], 1);
    sorted[p] = ((unsigned)i << 16) | (unsigned)i;
  }
  __syncthreads();
  // reserve global space: one atomicAdd per bucket per block
  int ntot = ntot_s;
  for (int b = tid; b < NB; b += APPT) {
    int end = (b < NB - 1) ? (int)ofs[b + 1] : ntot;
    int len = end - (int)ofs[b];
    cnt[b] = len ? atomicAdd(&cursors[b * CURSTRIDE], len) : 0;
  }
  __syncthreads();
  // coalesced flush (store local row id in high 16)
  for (int j = tid; j < ntot; j += APPT) {
    unsigned item = sorted[j];
    unsigned r = item >> 16;
    unsigned b = r / RPB;
    unsigned lr = r - b * RPB;
    int idx = cnt[b] + (j - (int)ofs[b]);
    if (idx < CAP) bucketmem[b * CAP + idx] = (lr << 16) | (item & 0xFFFFu);
  }
}

// -------- dedup: row-sequential, col-partitioned bitmaps (28 waves/CU) ------
__global__ __launch_bounds__(256, 7) void k_dedup(unsigned *bucketmem,
                                                  const int *cursors,
                                                  int *uniq_cnt) {
  int b = blockIdx.x;
  int rowbase = b * RPB;
  if (rowbase >= NN) { if (threadIdx.x == 0) uniq_cnt[b] = 0; return; }

  __shared__ unsigned short arr[CAP];  // 16 KB
  __shared__ int cnt[RPB];
  __shared__ int rowend[RPB];
  __shared__ int curs[RPB];
  __shared__ int rowoff[RPB];
  __shared__ unsigned bm[4][BMW];      // 5 KB col-partitioned bitmaps
  __shared__ unsigned sm[4][10];       // summaries (313 bits -> 10 words)
  __shared__ int wcnt[RPB][4];         // per-row per-wave unique counts

  int tid = threadIdx.x, lane = tid & 63, wid = tid >> 6;
  int n = cursors[b * CURSTRIDE]; if (n > CAP) n = CAP;
  const unsigned *src = bucketmem + (size_t)b * CAP;

  for (int i = tid; i < RPB; i += 256) cnt[i] = 0;
  __syncthreads();
  for (int j = tid; j < n; j += 256) atomicAdd(&cnt[src[j] >> 16], 1);
  __syncthreads();
  // wave0 parallel exclusive scan over RPB=40 rows
  if (wid == 0) {
    int v = (lane < RPB) ? cnt[lane] : 0;
    int x = v;
    for (int d = 1; d < 64; d <<= 1) {
      int y = __shfl_up(x, d, 64);
      if (lane >= d) x += y;
    }
    if (lane < RPB) { curs[lane] = x - v; rowend[lane] = x; }
  }
  __syncthreads();
  for (int j = tid; j < n; j += 256) {
    unsigned v = src[j];
    int p = atomicAdd(&curs[v >> 16], 1);
    arr[p] = (unsigned short)v;
  }
  for (int w = lane; w < BMW; w += 64) bm[wid][w] = 0u;
  if (lane < 10) sm[wid][lane] = 0u;
  __syncthreads();

  unsigned clo = (unsigned)wid * CSPAN;  // this wave's col range [clo,clo+CSPAN)
  for (int r = 0; r < RPB; r++) {
    int s1 = rowend[r], s0 = s1 - cnt[r];
    // all 4 waves scan the row; each keeps cols in its own range
    for (int j = s0 + lane; j < s1; j += 64) {
      unsigned wl = (unsigned)arr[j] - clo;   // wraps big if below range
      if (wl < CSPAN) {
        unsigned w = wl >> 5;
        atomicOr(&bm[wid][w], 1u << (wl & 31));
        atomicOr(&sm[wid][w >> 5], 1u << (w & 31));
      }
    }
    // count own-range uniques via summary
    unsigned s = (lane < 10) ? sm[wid][lane] : 0u;
    int m = 0;
    unsigned t = s;
    while (t) {
      int w = (lane << 5) + (__ffs(t) - 1);
      t &= t - 1;
      m += __popc(bm[wid][w]);
    }
    int x = m;
    for (int d = 1; d < 64; d <<= 1) {
      int y = __shfl_up(x, d, 64);
      if (lane >= d) x += y;
    }
    int mw = __shfl(x, 63, 64);   // wave-range total
    int lpre = x - m;             // lane-exclusive prefix within wave
    if (lane == 0) wcnt[r][wid] = mw;
    __syncthreads();              // one barrier per row (wcnt publish)
    int wpre = 0, tot = 0;
#pragma unroll
    for (int w = 0; w < 4; w++) {
      int v = wcnt[r][w];
      tot += v;
      if (w < wid) wpre += v;
    }
    // extract ascending in-place (uniques <= row entries; regions disjoint)
    int pos = s0 + wpre + lpre;
    t = s;
    while (t) {
      int w = (lane << 5) + (__ffs(t) - 1);
      t &= t - 1;
      unsigned mm = bm[wid][w];
      bm[wid][w] = 0u;
      unsigned cbase = clo + ((unsigned)w << 5);
      while (mm) {
        int bit = __ffs(mm) - 1;
        mm &= mm - 1;
        arr[pos++] = (unsigned short)(cbase + (unsigned)bit);
      }
    }
    if (lane < 10) sm[wid][lane] = 0u;
    if (tid == 0) cnt[r] = tot;
  }
  __syncthreads();
  // wave0 parallel exclusive scan of unique counts
  if (wid == 0) {
    int v = (lane < RPB) ? cnt[lane] : 0;
    int x = v;
    for (int d = 1; d < 64; d <<= 1) {
      int y = __shfl_up(x, d, 64);
      if (lane >= d) x += y;
    }
    if (lane < RPB) rowoff[lane] = x - v;
    if (lane == RPB - 1) uniq_cnt[b] = x;
  }
  __syncthreads();
  // write uniques as packed (row<<16)|col — ascending == hash order
  unsigned *dst = bucketmem + (size_t)b * CAP;
  for (int r = wid; r < RPB; r += 4) {
    int s0 = r ? rowend[r - 1] : 0;
    int u = cnt[r], o = rowoff[r];
    unsigned rowpack = (unsigned)(rowbase + r) << 16;
    for (int j = lane; j < u; j += 64)
      dst[o + j] = rowpack | (unsigned)arr[s0 + j];
  }
}

// ---------------- emit (fused offset-reduction + diag) ----------------
__global__ __launch_bounds__(256) void k_emit(const unsigned *bucketmem,
                                              const int *uniq_cnt, float *out,
                                              int E, int U) {
  __shared__ int part[4];
  int b = blockIdx.x;
  int tid = threadIdx.x, lane = tid & 63, wid = tid >> 6;
  // ob = sum of uniq_cnt[0..b) via masked butterfly reduction
  int acc = 0;
  for (int i = tid; i < NB; i += 256)
    if (i < b) acc += uniq_cnt[i];
  for (int d = 1; d < 64; d <<= 1) acc += __shfl_xor(acc, d, 64);
  if (lane == 0) part[wid] = acc;
  __syncthreads();
  int ob = part[0] + part[1] + part[2] + part[3];
  int ub = uniq_cnt[b];
  const unsigned *src = bucketmem + (size_t)b * CAP;
  int base3 = 3 * E;
  for (int j = tid; j < ub; j += 256) {
    unsigned h = src[j];
    unsigned r = h >> 16;
    unsigned c = h & 0xFFFFu;
    int idx = ob + j;
    if (idx < U) {
      out[base3 + idx] = (float)r;
      out[base3 + U + idx] = (float)c;
      out[base3 + 2 * U + idx] = 1.0f;
    }
  }
  if (b == NB - 1 && tid == 0) {
    int C = ob + ub;
    if (C != U) {
      int d = C - U; if (d < 0) d = -d; if (d > 60000) d = 60000;
      out[base3] = (float)(300000 + d); // sentinel (should never fire)
    }
  }
}

// ---------------- launch ----------------
extern "C" void kernel_launch(void *const *d_in, const int *in_sizes, int n_in,
                              void *d_out, int out_size, void *d_ws,
                              size_t ws_size, hipStream_t stream) {
  const int *rows = (const int *)d_in[0];
  const int *cols = (const int *)d_in[1];
  const int *seeds = (const int *)d_in[3];
  const int E = in_sizes[0];
  const int ns = in_sizes[3];
  float *out = (float *)d_out;
  const int U = (out_size - 3 * E) / 3;

  // ---- workspace carve ----
  int *I = (int *)d_ws;
  int *deg = I;      I += NN;               // zeroed in k_level0
  int *cursors = I;  I += NB * CURSTRIDE;   // zeroed in k_level0
  int *uniq_cnt = I; I += NB;               // fully written by k_dedup
  unsigned char *cur = (unsigned char *)I;  // 3*NN bytes zeroed by k_zero16
  unsigned char *touched = cur + NN;
  unsigned char *mask_bfs = touched + NN;
  size_t zero_bytes = (size_t)(3 * NN);     // cur+touched+mask_bfs only
  int *J = (int *)(mask_bfs + NN);
  int *tem_num = J;  J += 1;
  J += 1; // pad to 8B
  int *mask_part = J; J += 40;              // popcount partials (fully written)
  unsigned short *mask_idx = (unsigned short *)J;
  J += NN / 2; // 40000 ushorts = 20000 ints
  unsigned *bucketmem = (unsigned *)J; J += (size_t)NB * CAP; // 32 MB
  unsigned char *alive = (unsigned char *)J; // E bytes (fully written)

  // ---- host key derivation (v0): key(1)=(0,1); split(3); randint split(2) ----
  unsigned F[3][2];
  tf2x32(0u, 1u, 0u, 0u, F[0][0], F[0][1]); // kS
  tf2x32(0u, 1u, 0u, 1u, F[1][0], F[1][1]); // kR
  tf2x32(0u, 1u, 0u, 2u, F[2][0], F[2][1]); // kC
  unsigned K[3][4];
  for (int s = 0; s < 3; s++) {
    tf2x32(F[s][0], F[s][1], 0u, 0u, K[s][0], K[s][1]); // k1 (higher bits)
    tf2x32(F[s][0], F[s][1], 0u, 1u, K[s][2], K[s][3]); // k2 (lower bits)
  }

  dim3 b(256);
  int gE = (E + 255) / 256;
  int gSS = (SAMPN + 255) / 256; // covers ns=2000 too
  int gT = (E + EPB - 1) / EPB;  // 455; also covers self nodes (455*88>=NN)
  int n16 = (int)(zero_bytes / 16);

  k_zero16<<<(n16 + 255) / 256, b, 0, stream>>>((uint4 *)cur, n16);
  k_seed_samp<<<gSS, b, 0, stream>>>(seeds, ns, cur, mask_bfs,
                                     K[0][0], K[0][1], K[0][2], K[0][3]);
  k_level0<<<gE, b, 0, stream>>>(rows, cols, E, cur, alive, touched, mask_bfs,
                                 deg, cursors);
  k_level1_deg<<<gE, b, 0, stream>>>(rows, cols, E, touched, alive, deg,
                                     (const unsigned *)mask_bfs, mask_part);
  k_mask_extract<<<40, b, 0, stream>>>((const unsigned *)mask_bfs, mask_part,
                                       mask_idx, tem_num);
  k_append<<<gT, dim3(APPT), 0, stream>>>(rows, cols, alive, deg, mask_idx,
                                          tem_num, cursors, bucketmem, out,
                                          K[1][0], K[1][1], K[1][2], K[1][3],
                                          K[2][0], K[2][1], K[2][2], K[2][3], E);
  k_dedup<<<NB, b, 0, stream>>>(bucketmem, cursors, uniq_cnt);
  k_emit<<<NB, b, 0, stream>>>(bucketmem, uniq_cnt, out, E, U);
}

// Round 9
// 253.518 us; speedup vs baseline: 1.2579x; 1.2579x over previous
//
#include <hip/hip_runtime.h>
#include <stdint.h>

// RandomMaskSubgraphs — round 22: r18 config (best, 250.5us) + per-wave
// dedup binning counters (surgical, structure-preserving).
// r21 post-mortem: col-partitioned dedup raised occupancy (19->39%) but 4x'd
// the row-scan work + 40 serial barriers -> 117us. LESSON: occupancy bought
// by multiplying work is a loss. Wave-per-row dedup structure is right.
// r22 dedup fix: count+scatter passes did ~5.3k LDS atomics onto 40 addrs
// from 256 threads (6.4-way ~2.3x serialization, m136). Now: 4 wave-chunks,
// per-wave counters wc[4][40] (1.6-way, near-free), wave0 merges + computes
// per-wave scatter bases wcur[4][40]; scatter hits private cursors only.
// Order within row becomes wave-chunked — irrelevant (bitmap erases order).
// LDS 37.7->38.8KB, still 4 blocks/CU. Bitmap/extract phase untouched.
// RULES: no intra-kernel grid sync (r16); no cursor padding (r19); NB=1024,
// RPB=40 (r20); no col-partition/per-row barriers (r21).
// PRNG v0 bit-exact since r4.

#define NN 40000
#define SAMPN (NN / 2)
#define WORDS 1250               // col bitmap words (40000/32)
#define SWORDS 40                // summary words
#define NB 1024                  // buckets (append bins == dedup blocks)
#define RPB 40                   // rows per bucket (1024*40 >= 40000)
#define CAP 8192                 // entries per bucket (mean ~5.3k)
#define CURSTRIDE 4
#define APPT 512                 // k_append threads per block
#define EPB 5632                 // edges per append block (11*512)
#define NE (EPB / APPT)          // 11 edges per thread
#define SELFPB 88                // self nodes per append block (455*88 >= 40000)
#define SCAP (3 * EPB + SELFPB)  // 16984 -> 67.9 KB
#define MWPB 250                 // mask words per extract block (40*250=10000)

// ---------------- Threefry-2x32 (20 rounds, JAX schedule) ----------------
__host__ __device__ __forceinline__ void tf2x32(unsigned k0, unsigned k1,
                                                unsigned x0, unsigned x1,
                                                unsigned &o0, unsigned &o1) {
  unsigned ks2 = k0 ^ k1 ^ 0x1BD11BDAu;
  x0 += k0; x1 += k1;
#define TFR(r) { x0 += x1; x1 = (x1 << (r)) | (x1 >> (32 - (r))); x1 ^= x0; }
  TFR(13) TFR(15) TFR(26) TFR(6)
  x0 += k1;  x1 += ks2 + 1u;
  TFR(17) TFR(29) TFR(16) TFR(24)
  x0 += ks2; x1 += k0 + 2u;
  TFR(13) TFR(15) TFR(26) TFR(6)
  x0 += k0;  x1 += k1 + 3u;
  TFR(17) TFR(29) TFR(16) TFR(24)
  x0 += k1;  x1 += ks2 + 4u;
  TFR(13) TFR(15) TFR(26) TFR(6)
  x0 += ks2; x1 += k0 + 5u;
#undef TFR
  o0 = x0; o1 = x1;
}

// jax.random.randint element e with pre-split subkeys k1=(a,b), k2=(c,d).
// m2 = ((65536 % span)^2) % span, precomputed by the caller (span-invariant).
__device__ __forceinline__ unsigned jrand(unsigned a, unsigned b, unsigned c,
                                          unsigned d, unsigned e, unsigned span,
                                          unsigned m2) {
  unsigned x0, x1, y0, y1;
  tf2x32(a, b, 0u, e, x0, x1);
  unsigned hi = x0 ^ x1;
  tf2x32(c, d, 0u, e, y0, y1);
  unsigned lo = y0 ^ y1;
  return ((hi % span) * m2 + (lo % span)) % span;
}

// ---------------- init / BFS ----------------
__global__ void k_zero16(uint4 *p, int n16) {
  int i = blockIdx.x * blockDim.x + threadIdx.x;
  if (i < n16) p[i] = make_uint4(0u, 0u, 0u, 0u);
}
__global__ void k_seed_samp(const int *seeds, int ns, unsigned char *cur,
                            unsigned char *mask_bfs,
                            unsigned a, unsigned b, unsigned c, unsigned d) {
  int i = blockIdx.x * blockDim.x + threadIdx.x;
  if (i < ns) { int s = seeds[i]; cur[s] = 1; mask_bfs[s] = 1; }
  if (i < SAMPN) {
    constexpr unsigned M2 =
        ((65536u % (unsigned)NN) * (65536u % (unsigned)NN)) % (unsigned)NN;
    unsigned idx = jrand(a, b, c, d, (unsigned)i, (unsigned)NN, M2);
    mask_bfs[idx] = 1;
  }
}
// level-0 BFS; also zeroes deg + cursors (used by later kernels only).
__global__ void k_level0(const int *rows, const int *cols, int E,
                         const unsigned char *cur, unsigned char *alive,
                         unsigned char *touched, unsigned char *mask_bfs,
                         int *deg, int *cursors) {
  int e = blockIdx.x * blockDim.x + threadIdx.x;
  if (e < NN) deg[e] = 0;
  int e2 = e - NN;
  if (e2 >= 0 && e2 < NB * CURSTRIDE) cursors[e2] = 0;
  if (e >= E) return;
  int r = rows[e], c = cols[e];
  if (cur[r] | cur[c]) {
    alive[e] = 0;
    touched[r] = 1; touched[c] = 1;
    mask_bfs[r] = 1; mask_bfs[c] = 1;
  } else alive[e] = 1;
}
// level-1 BFS + degree; blocks 0..39 also compute mask popcount partials
// (mask_bfs is complete before this kernel launches).
__global__ void k_level1_deg(const int *rows, const int *cols, int E,
                             const unsigned char *touched, unsigned char *alive,
                             int *deg, const unsigned *maskw, int *mask_part) {
  int tid = threadIdx.x;
  int e = blockIdx.x * blockDim.x + tid;
  if (e < E && alive[e]) {
    int r = rows[e];
    if (touched[r] | touched[cols[e]]) alive[e] = 0;
    else atomicAdd(&deg[r], 1);
  }
  if (blockIdx.x < 40) {
    __shared__ int red[4];
    int lane = tid & 63, wid = tid >> 6;
    int c = (tid < MWPB) ? __popc(maskw[blockIdx.x * MWPB + tid]) : 0;
    for (int d = 1; d < 64; d <<= 1) c += __shfl_xor(c, d, 64);
    if (lane == 0) red[wid] = c;
    __syncthreads();
    if (tid == 0) mask_part[blockIdx.x] = red[0] + red[1] + red[2] + red[3];
  }
}

// ---------------- mask extraction (40 blocks; replaces 1-block scan) --------
__global__ __launch_bounds__(256) void k_mask_extract(const unsigned *f,
                                                      const int *mask_part,
                                                      unsigned short *mask_idx,
                                                      int *tem_num) {
  __shared__ int wsum[4];
  __shared__ int basech;
  int b = blockIdx.x, tid = threadIdx.x, lane = tid & 63, wid = tid >> 6;
  if (wid == 0) {
    int v = (lane < 40) ? mask_part[lane] : 0;
    int x = v;
    for (int d = 1; d < 64; d <<= 1) {
      int y = __shfl_up(x, d, 64);
      if (lane >= d) x += y;
    }
    int basev = __shfl(x - v, b, 64);   // exclusive prefix at own block
    int total = __shfl(x, 39, 64);
    if (lane == 0) {
      basech = basev;
      if (b == 0) *tem_num = total;
    }
  }
  int w = b * MWPB + tid;
  unsigned u = (tid < MWPB) ? f[w] : 0u;
  int c = __popc(u);
  int x = c;
  for (int d = 1; d < 64; d <<= 1) {
    int y = __shfl_up(x, d, 64);
    if (lane >= d) x += y;
  }
  if (lane == 63) wsum[wid] = x;
  __syncthreads();
  if (wid == 0) {
    int v = (lane < 4) ? wsum[lane] : 0;
    int y = v;
    for (int d = 1; d < 4; d <<= 1) {
      int z = __shfl_up(y, d, 64);
      if (lane >= d) y += z;
    }
    if (lane < 4) wsum[lane] = y - v;
  }
  __syncthreads();
  int off = basech + wsum[wid] + (x - c);
  while (u) {
    int byte = (__ffs(u) - 1) >> 3;
    u &= u - 1;
    mask_idx[off++] = (unsigned short)(w * 4 + byte);
  }
}

// ---------------- binned append (tem + alive + self) + fused encoder ----------
__global__ __launch_bounds__(APPT) void k_append(
    const int *rows, const int *cols, const unsigned char *alive,
    const int *deg, const unsigned short *mask_idx, const int *tem_num,
    int *cursors, unsigned *bucketmem, float *out,
    unsigned ra, unsigned rb, unsigned rc, unsigned rd,
    unsigned ca, unsigned cb, unsigned cc, unsigned cd, int E) {
  __shared__ unsigned sorted[SCAP];     // 67.9 KB
  __shared__ int cnt[NB];               // 4 KB
  __shared__ unsigned short ofs[NB];    // 2 KB
  __shared__ int ntot_s;
  int tid = threadIdx.x, lane = tid & 63, wid = tid >> 6;
  int e0 = blockIdx.x * EPB;
  int i0 = blockIdx.x * SELFPB;         // self-node range
  int i1 = i0 + SELFPB; if (i1 > NN) i1 = NN;
  unsigned span = (unsigned)*tem_num;
  unsigned mtmp = 65536u % span;
  unsigned m2 = (mtmp * mtmp) % span;   // hoisted out of jrand (span-invariant)
  const unsigned NOPE = 0xFFFFFFFFu;

  unsigned tval[NE], aval[NE];

  for (int i = tid; i < NB; i += APPT) cnt[i] = 0;
  __syncthreads();
  // pass A: draw + gather once, count, cache in registers; fused encoder out
#pragma unroll
  for (int k = 0; k < NE; k++) {
    int e = e0 + k * APPT + tid;
    if (e < E) {
      unsigned iR = jrand(ra, rb, rc, rd, (unsigned)e, span, m2);
      unsigned iC = jrand(ca, cb, cc, cd, (unsigned)e, span, m2);
      unsigned tr = (unsigned)mask_idx[iR], tc = (unsigned)mask_idx[iC];
      tval[k] = (tr << 16) | tc;
      atomicAdd(&cnt[tr / RPB], 1);
      atomicAdd(&cnt[tc / RPB], 1);
      int r = rows[e], c = cols[e];
      float v = 0.0f;
      if (alive[e]) {
        aval[k] = ((unsigned)r << 16) | (unsigned)c;
        atomicAdd(&cnt[(unsigned)r / RPB], 1);
        float xr = (float)deg[r] + 1e-12f;
        float xc = (float)deg[c] + 1e-12f;
        float dr = (float)(1.0 / sqrt((double)xr));
        float dc = (float)(1.0 / sqrt((double)xc));
        v = dr * dc;
      } else aval[k] = NOPE;
      out[e] = (float)r;
      out[E + e] = (float)c;
      out[2 * E + e] = v;
    } else { tval[k] = NOPE; aval[k] = NOPE; }
  }
  for (int i = i0 + tid; i < i1; i += APPT) atomicAdd(&cnt[i / RPB], 1);
  __syncthreads();
  // exclusive scan of cnt[1024] by wave 0 -> ofs (ushort)
  if (wid == 0) {
    int carry = 0;
    for (int c8 = 0; c8 < NB / 64; c8++) {
      int v = cnt[c8 * 64 + lane];
      int x = v;
      for (int d = 1; d < 64; d <<= 1) {
        int y = __shfl_up(x, d, 64);
        if (lane >= d) x += y;
      }
      ofs[c8 * 64 + lane] = (unsigned short)(carry + x - v);
      carry += __shfl(x, 63, 64);
    }
    if (lane == 0) ntot_s = carry;
  }
  __syncthreads();
  for (int i = tid; i < NB; i += APPT) cnt[i] = ofs[i];
  __syncthreads();
  // pass B: scatter from registers (+ self)
#pragma unroll
  for (int k = 0; k < NE; k++) {
    unsigned v = tval[k];
    if (v != NOPE) {
      unsigned tr = v >> 16, tc = v & 0xFFFFu;
      int p1 = atomicAdd(&cnt[tr / RPB], 1);
      sorted[p1] = v;
      int p2 = atomicAdd(&cnt[tc / RPB], 1);
      sorted[p2] = (tc << 16) | tr;
      unsigned a = aval[k];
      if (a != NOPE) {
        int p3 = atomicAdd(&cnt[(a >> 16) / RPB], 1);
        sorted[p3] = a;
      }
    }
  }
  for (int i = i0 + tid; i < i1; i += APPT) {
    int p = atomicAdd(&cnt[i / RPB], 1);
    sorted[p] = ((unsigned)i << 16) | (unsigned)i;
  }
  __syncthreads();
  // reserve global space: one atomicAdd per bucket per block
  int ntot = ntot_s;
  for (int b = tid; b < NB; b += APPT) {
    int end = (b < NB - 1) ? (int)ofs[b + 1] : ntot;
    int len = end - (int)ofs[b];
    cnt[b] = len ? atomicAdd(&cursors[b * CURSTRIDE], len) : 0;
  }
  __syncthreads();
  // coalesced flush (store local row id in high 16)
  for (int j = tid; j < ntot; j += APPT) {
    unsigned item = sorted[j];
    unsigned r = item >> 16;
    unsigned b = r / RPB;
    unsigned lr = r - b * RPB;
    int idx = cnt[b] + (j - (int)ofs[b]);
    if (idx < CAP) bucketmem[b * CAP + idx] = (lr << 16) | (item & 0xFFFFu);
  }
}

// ---- dedup: wave-per-row bitmaps; per-wave binning counters (low conflict) --
__global__ __launch_bounds__(256) void k_dedup(unsigned *bucketmem,
                                               const int *cursors, int *uniq_cnt) {
  int b = blockIdx.x;
  int rowbase = b * RPB;
  if (rowbase >= NN) { if (threadIdx.x == 0) uniq_cnt[b] = 0; return; }

  __shared__ unsigned short arr[CAP];  // 16 KB
  __shared__ int wc[4][RPB];           // per-wave row counts (640 B)
  __shared__ int wcur[4][RPB];         // per-wave scatter cursors (640 B)
  __shared__ int cnt[RPB];             // row totals, then per-row uniques
  __shared__ int rowend[RPB];
  __shared__ int rowoff[RPB];
  __shared__ unsigned bm[4][WORDS];    // 20 KB wave-private bitmaps
  __shared__ unsigned sm[4][SWORDS];

  int tid = threadIdx.x, lane = tid & 63, wid = tid >> 6;
  int n = cursors[b * CURSTRIDE]; if (n > CAP) n = CAP;
  const unsigned *src = bucketmem + (size_t)b * CAP;

  // wave-contiguous chunks: wave w handles [w*n4, min(n,(w+1)*n4))
  int n4 = (n + 3) >> 2;
  int j0 = wid * n4;
  int j1 = j0 + n4; if (j1 > n) j1 = n;

  for (int i = tid; i < 4 * RPB; i += 256) ((int *)wc)[i] = 0;
  __syncthreads();
  for (int j = j0 + lane; j < j1; j += 64)
    atomicAdd(&wc[wid][src[j] >> 16], 1);   // 64 lanes -> 40 ctrs: ~1.6-way
  __syncthreads();
  // wave0: row totals, row-start scan, per-wave scatter bases
  if (wid == 0) {
    int c0 = 0, c1 = 0, c2 = 0, c3 = 0, v = 0;
    if (lane < RPB) {
      c0 = wc[0][lane]; c1 = wc[1][lane];
      c2 = wc[2][lane]; c3 = wc[3][lane];
      v = c0 + c1 + c2 + c3;
    }
    int x = v;
    for (int d = 1; d < 64; d <<= 1) {
      int y = __shfl_up(x, d, 64);
      if (lane >= d) x += y;
    }
    if (lane < RPB) {
      int start = x - v;
      rowend[lane] = x;
      cnt[lane] = v;
      wcur[0][lane] = start;
      wcur[1][lane] = start + c0;
      wcur[2][lane] = start + c0 + c1;
      wcur[3][lane] = start + c0 + c1 + c2;
    }
  }
  __syncthreads();
  for (int j = j0 + lane; j < j1; j += 64) {
    unsigned v = src[j];
    int p = atomicAdd(&wcur[wid][v >> 16], 1);  // private cursors: ~1.6-way
    arr[p] = (unsigned short)v;
  }
  for (int w = lane; w < WORDS; w += 64) bm[wid][w] = 0u;
  if (lane < SWORDS) sm[wid][lane] = 0u;
  __syncthreads();

  for (int r = wid; r < RPB; r += 4) {
    int s1 = rowend[r], s0 = s1 - cnt[r];
    for (int j = s0 + lane; j < s1; j += 64) {
      unsigned c = arr[j];
      atomicOr(&bm[wid][c >> 5], 1u << (c & 31));
      atomicOr(&sm[wid][c >> 10], 1u << ((c >> 5) & 31));
    }
    unsigned s = (lane < SWORDS) ? sm[wid][lane] : 0u;
    int m = 0;
    unsigned t = s;
    while (t) {
      int w = (lane << 5) + (__ffs(t) - 1);
      t &= t - 1;
      m += __popc(bm[wid][w]);
    }
    int x = m;
    for (int d = 1; d < 64; d <<= 1) {
      int y = __shfl_up(x, d, 64);
      if (lane >= d) x += y;
    }
    int u = __shfl(x, 63, 64);
    int pos = s0 + (x - m);
    t = s;
    while (t) {
      int w = (lane << 5) + (__ffs(t) - 1);
      t &= t - 1;
      unsigned mm = bm[wid][w];
      bm[wid][w] = 0u;
      while (mm) {
        int bit = __ffs(mm) - 1;
        mm &= mm - 1;
        arr[pos++] = (unsigned short)((w << 5) + bit);
      }
    }
    if (lane < SWORDS) sm[wid][lane] = 0u;
    if (lane == 0) cnt[r] = u;
  }
  __syncthreads();
  // wave0 parallel exclusive scan of unique counts
  if (wid == 0) {
    int v = (lane < RPB) ? cnt[lane] : 0;
    int x = v;
    for (int d = 1; d < 64; d <<= 1) {
      int y = __shfl_up(x, d, 64);
      if (lane >= d) x += y;
    }
    if (lane < RPB) rowoff[lane] = x - v;
    if (lane == RPB - 1) uniq_cnt[b] = x;
  }
  __syncthreads();
  // write uniques as packed (row<<16)|col — ascending == hash order
  unsigned *dst = bucketmem + (size_t)b * CAP;
  for (int r = wid; r < RPB; r += 4) {
    int s0 = r ? rowend[r - 1] : 0;
    int u = cnt[r], o = rowoff[r];
    unsigned rowpack = (unsigned)(rowbase + r) << 16;
    for (int j = lane; j < u; j += 64)
      dst[o + j] = rowpack | (unsigned)arr[s0 + j];
  }
}

// ---------------- emit (fused offset-reduction + diag) ----------------
__global__ __launch_bounds__(256) void k_emit(const unsigned *bucketmem,
                                              const int *uniq_cnt, float *out,
                                              int E, int U) {
  __shared__ int part[4];
  int b = blockIdx.x;
  int tid = threadIdx.x, lane = tid & 63, wid = tid >> 6;
  // ob = sum of uniq_cnt[0..b) via masked butterfly reduction
  int acc = 0;
  for (int i = tid; i < NB; i += 256)
    if (i < b) acc += uniq_cnt[i];
  for (int d = 1; d < 64; d <<= 1) acc += __shfl_xor(acc, d, 64);
  if (lane == 0) part[wid] = acc;
  __syncthreads();
  int ob = part[0] + part[1] + part[2] + part[3];
  int ub = uniq_cnt[b];
  const unsigned *src = bucketmem + (size_t)b * CAP;
  int base3 = 3 * E;
  for (int j = tid; j < ub; j += 256) {
    unsigned h = src[j];
    unsigned r = h >> 16;
    unsigned c = h & 0xFFFFu;
    int idx = ob + j;
    if (idx < U) {
      out[base3 + idx] = (float)r;
      out[base3 + U + idx] = (float)c;
      out[base3 + 2 * U + idx] = 1.0f;
    }
  }
  if (b == NB - 1 && tid == 0) {
    int C = ob + ub;
    if (C != U) {
      int d = C - U; if (d < 0) d = -d; if (d > 60000) d = 60000;
      out[base3] = (float)(300000 + d); // sentinel (should never fire)
    }
  }
}

// ---------------- launch ----------------
extern "C" void kernel_launch(void *const *d_in, const int *in_sizes, int n_in,
                              void *d_out, int out_size, void *d_ws,
                              size_t ws_size, hipStream_t stream) {
  const int *rows = (const int *)d_in[0];
  const int *cols = (const int *)d_in[1];
  const int *seeds = (const int *)d_in[3];
  const int E = in_sizes[0];
  const int ns = in_sizes[3];
  float *out = (float *)d_out;
  const int U = (out_size - 3 * E) / 3;

  // ---- workspace carve ----
  int *I = (int *)d_ws;
  int *deg = I;      I += NN;               // zeroed in k_level0
  int *cursors = I;  I += NB * CURSTRIDE;   // zeroed in k_level0
  int *uniq_cnt = I; I += NB;               // fully written by k_dedup
  unsigned char *cur = (unsigned char *)I;  // 3*NN bytes zeroed by k_zero16
  unsigned char *touched = cur + NN;
  unsigned char *mask_bfs = touched + NN;
  size_t zero_bytes = (size_t)(3 * NN);     // cur+touched+mask_bfs only
  int *J = (int *)(mask_bfs + NN);
  int *tem_num = J;  J += 1;
  J += 1; // pad to 8B
  int *mask_part = J; J += 40;              // popcount partials (fully written)
  unsigned short *mask_idx = (unsigned short *)J;
  J += NN / 2; // 40000 ushorts = 20000 ints
  unsigned *bucketmem = (unsigned *)J; J += (size_t)NB * CAP; // 32 MB
  unsigned char *alive = (unsigned char *)J; // E bytes (fully written)

  // ---- host key derivation (v0): key(1)=(0,1); split(3); randint split(2) ----
  unsigned F[3][2];
  tf2x32(0u, 1u, 0u, 0u, F[0][0], F[0][1]); // kS
  tf2x32(0u, 1u, 0u, 1u, F[1][0], F[1][1]); // kR
  tf2x32(0u, 1u, 0u, 2u, F[2][0], F[2][1]); // kC
  unsigned K[3][4];
  for (int s = 0; s < 3; s++) {
    tf2x32(F[s][0], F[s][1], 0u, 0u, K[s][0], K[s][1]); // k1 (higher bits)
    tf2x32(F[s][0], F[s][1], 0u, 1u, K[s][2], K[s][3]); // k2 (lower bits)
  }

  dim3 b(256);
  int gE = (E + 255) / 256;
  int gSS = (SAMPN + 255) / 256; // covers ns=2000 too
  int gT = (E + EPB - 1) / EPB;  // 455; also covers self nodes (455*88>=NN)
  int n16 = (int)(zero_bytes / 16);

  k_zero16<<<(n16 + 255) / 256, b, 0, stream>>>((uint4 *)cur, n16);
  k_seed_samp<<<gSS, b, 0, stream>>>(seeds, ns, cur, mask_bfs,
                                     K[0][0], K[0][1], K[0][2], K[0][3]);
  k_level0<<<gE, b, 0, stream>>>(rows, cols, E, cur, alive, touched, mask_bfs,
                                 deg, cursors);
  k_level1_deg<<<gE, b, 0, stream>>>(rows, cols, E, touched, alive, deg,
                                     (const unsigned *)mask_bfs, mask_part);
  k_mask_extract<<<40, b, 0, stream>>>((const unsigned *)mask_bfs, mask_part,
                                       mask_idx, tem_num);
  k_append<<<gT, dim3(APPT), 0, stream>>>(rows, cols, alive, deg, mask_idx,
                                          tem_num, cursors, bucketmem, out,
                                          K[1][0], K[1][1], K[1][2], K[1][3],
                                          K[2][0], K[2][1], K[2][2], K[2][3], E);
  k_dedup<<<NB, b, 0, stream>>>(bucketmem, cursors, uniq_cnt);
  k_emit<<<NB, b, 0, stream>>>(bucketmem, uniq_cnt, out, E, U);
}

// Round 10
// 252.141 us; speedup vs baseline: 1.2648x; 1.0055x over previous
//
#include <hip/hip_runtime.h>
#include <stdint.h>

// RandomMaskSubgraphs — round 23: third application of the only proven lever
// (fewer/fatter append blocks). r22 post-mortem: per-wave dedup counters
// neutral-to-worse (binning atomics were not the cost; dedup redesigns 0/3)
// -> dedup reverted to r18 form exactly.
// r23: APPT 512->1024, EPB 11264 (NE=11 unchanged), SELFPB 176 -> 228 blocks,
// LDS ~142KB -> 1 block/CU x 16 waves (same residency). Overhead instances
// halve (455->228); flush segments 17->~33 entries -> WRITE ~67->~62MB.
// Cost: 228<256 CUs (11% idle). Predicted append 55->~50, total ~247.
// RULES: no intra-kernel grid sync (r16); no cursor padding (r19); NB=1024/
// RPB=40 (r20); no col-partition dedup (r21); no per-wave dedup ctrs (r22).
// PRNG v0 bit-exact since r4.

#define NN 40000
#define SAMPN (NN / 2)
#define WORDS 1250               // col bitmap words (40000/32)
#define SWORDS 40                // summary words
#define NB 1024                  // buckets (append bins == dedup blocks)
#define RPB 40                   // rows per bucket (1024*40 >= 40000)
#define CAP 8192                 // entries per bucket (mean ~5.3k)
#define CURSTRIDE 4
#define APPT 1024                // k_append threads per block
#define EPB 11264                // edges per append block (11*1024)
#define NE (EPB / APPT)          // 11 edges per thread
#define SELFPB 176               // self nodes per append block (228*176 >= 40000)
#define SCAP (3 * EPB + SELFPB)  // 33968 -> 135.9 KB
#define MWPB 250                 // mask words per extract block (40*250=10000)

// ---------------- Threefry-2x32 (20 rounds, JAX schedule) ----------------
__host__ __device__ __forceinline__ void tf2x32(unsigned k0, unsigned k1,
                                                unsigned x0, unsigned x1,
                                                unsigned &o0, unsigned &o1) {
  unsigned ks2 = k0 ^ k1 ^ 0x1BD11BDAu;
  x0 += k0; x1 += k1;
#define TFR(r) { x0 += x1; x1 = (x1 << (r)) | (x1 >> (32 - (r))); x1 ^= x0; }
  TFR(13) TFR(15) TFR(26) TFR(6)
  x0 += k1;  x1 += ks2 + 1u;
  TFR(17) TFR(29) TFR(16) TFR(24)
  x0 += ks2; x1 += k0 + 2u;
  TFR(13) TFR(15) TFR(26) TFR(6)
  x0 += k0;  x1 += k1 + 3u;
  TFR(17) TFR(29) TFR(16) TFR(24)
  x0 += k1;  x1 += ks2 + 4u;
  TFR(13) TFR(15) TFR(26) TFR(6)
  x0 += ks2; x1 += k0 + 5u;
#undef TFR
  o0 = x0; o1 = x1;
}

// jax.random.randint element e with pre-split subkeys k1=(a,b), k2=(c,d).
// m2 = ((65536 % span)^2) % span, precomputed by the caller (span-invariant).
__device__ __forceinline__ unsigned jrand(unsigned a, unsigned b, unsigned c,
                                          unsigned d, unsigned e, unsigned span,
                                          unsigned m2) {
  unsigned x0, x1, y0, y1;
  tf2x32(a, b, 0u, e, x0, x1);
  unsigned hi = x0 ^ x1;
  tf2x32(c, d, 0u, e, y0, y1);
  unsigned lo = y0 ^ y1;
  return ((hi % span) * m2 + (lo % span)) % span;
}

// ---------------- init / BFS ----------------
__global__ void k_zero16(uint4 *p, int n16) {
  int i = blockIdx.x * blockDim.x + threadIdx.x;
  if (i < n16) p[i] = make_uint4(0u, 0u, 0u, 0u);
}
__global__ void k_seed_samp(const int *seeds, int ns, unsigned char *cur,
                            unsigned char *mask_bfs,
                            unsigned a, unsigned b, unsigned c, unsigned d) {
  int i = blockIdx.x * blockDim.x + threadIdx.x;
  if (i < ns) { int s = seeds[i]; cur[s] = 1; mask_bfs[s] = 1; }
  if (i < SAMPN) {
    constexpr unsigned M2 =
        ((65536u % (unsigned)NN) * (65536u % (unsigned)NN)) % (unsigned)NN;
    unsigned idx = jrand(a, b, c, d, (unsigned)i, (unsigned)NN, M2);
    mask_bfs[idx] = 1;
  }
}
// level-0 BFS; also zeroes deg + cursors (used by later kernels only).
__global__ void k_level0(const int *rows, const int *cols, int E,
                         const unsigned char *cur, unsigned char *alive,
                         unsigned char *touched, unsigned char *mask_bfs,
                         int *deg, int *cursors) {
  int e = blockIdx.x * blockDim.x + threadIdx.x;
  if (e < NN) deg[e] = 0;
  int e2 = e - NN;
  if (e2 >= 0 && e2 < NB * CURSTRIDE) cursors[e2] = 0;
  if (e >= E) return;
  int r = rows[e], c = cols[e];
  if (cur[r] | cur[c]) {
    alive[e] = 0;
    touched[r] = 1; touched[c] = 1;
    mask_bfs[r] = 1; mask_bfs[c] = 1;
  } else alive[e] = 1;
}
// level-1 BFS + degree; blocks 0..39 also compute mask popcount partials
// (mask_bfs is complete before this kernel launches).
__global__ void k_level1_deg(const int *rows, const int *cols, int E,
                             const unsigned char *touched, unsigned char *alive,
                             int *deg, const unsigned *maskw, int *mask_part) {
  int tid = threadIdx.x;
  int e = blockIdx.x * blockDim.x + tid;
  if (e < E && alive[e]) {
    int r = rows[e];
    if (touched[r] | touched[cols[e]]) alive[e] = 0;
    else atomicAdd(&deg[r], 1);
  }
  if (blockIdx.x < 40) {
    __shared__ int red[4];
    int lane = tid & 63, wid = tid >> 6;
    int c = (tid < MWPB) ? __popc(maskw[blockIdx.x * MWPB + tid]) : 0;
    for (int d = 1; d < 64; d <<= 1) c += __shfl_xor(c, d, 64);
    if (lane == 0) red[wid] = c;
    __syncthreads();
    if (tid == 0) mask_part[blockIdx.x] = red[0] + red[1] + red[2] + red[3];
  }
}

// ---------------- mask extraction (40 blocks; replaces 1-block scan) --------
__global__ __launch_bounds__(256) void k_mask_extract(const unsigned *f,
                                                      const int *mask_part,
                                                      unsigned short *mask_idx,
                                                      int *tem_num) {
  __shared__ int wsum[4];
  __shared__ int basech;
  int b = blockIdx.x, tid = threadIdx.x, lane = tid & 63, wid = tid >> 6;
  if (wid == 0) {
    int v = (lane < 40) ? mask_part[lane] : 0;
    int x = v;
    for (int d = 1; d < 64; d <<= 1) {
      int y = __shfl_up(x, d, 64);
      if (lane >= d) x += y;
    }
    int basev = __shfl(x - v, b, 64);   // exclusive prefix at own block
    int total = __shfl(x, 39, 64);
    if (lane == 0) {
      basech = basev;
      if (b == 0) *tem_num = total;
    }
  }
  int w = b * MWPB + tid;
  unsigned u = (tid < MWPB) ? f[w] : 0u;
  int c = __popc(u);
  int x = c;
  for (int d = 1; d < 64; d <<= 1) {
    int y = __shfl_up(x, d, 64);
    if (lane >= d) x += y;
  }
  if (lane == 63) wsum[wid] = x;
  __syncthreads();
  if (wid == 0) {
    int v = (lane < 4) ? wsum[lane] : 0;
    int y = v;
    for (int d = 1; d < 4; d <<= 1) {
      int z = __shfl_up(y, d, 64);
      if (lane >= d) y += z;
    }
    if (lane < 4) wsum[lane] = y - v;
  }
  __syncthreads();
  int off = basech + wsum[wid] + (x - c);
  while (u) {
    int byte = (__ffs(u) - 1) >> 3;
    u &= u - 1;
    mask_idx[off++] = (unsigned short)(w * 4 + byte);
  }
}

// ---------------- binned append (tem + alive + self) + fused encoder ----------
__global__ __launch_bounds__(APPT) void k_append(
    const int *rows, const int *cols, const unsigned char *alive,
    const int *deg, const unsigned short *mask_idx, const int *tem_num,
    int *cursors, unsigned *bucketmem, float *out,
    unsigned ra, unsigned rb, unsigned rc, unsigned rd,
    unsigned ca, unsigned cb, unsigned cc, unsigned cd, int E) {
  __shared__ unsigned sorted[SCAP];     // 135.9 KB
  __shared__ int cnt[NB];               // 4 KB
  __shared__ unsigned short ofs[NB];    // 2 KB
  __shared__ int ntot_s;
  int tid = threadIdx.x, lane = tid & 63, wid = tid >> 6;
  int e0 = blockIdx.x * EPB;
  int i0 = blockIdx.x * SELFPB;         // self-node range
  int i1 = i0 + SELFPB; if (i1 > NN) i1 = NN;
  unsigned span = (unsigned)*tem_num;
  unsigned mtmp = 65536u % span;
  unsigned m2 = (mtmp * mtmp) % span;   // hoisted out of jrand (span-invariant)
  const unsigned NOPE = 0xFFFFFFFFu;

  unsigned tval[NE], aval[NE];

  for (int i = tid; i < NB; i += APPT) cnt[i] = 0;
  __syncthreads();
  // pass A: draw + gather once, count, cache in registers; fused encoder out
#pragma unroll
  for (int k = 0; k < NE; k++) {
    int e = e0 + k * APPT + tid;
    if (e < E) {
      unsigned iR = jrand(ra, rb, rc, rd, (unsigned)e, span, m2);
      unsigned iC = jrand(ca, cb, cc, cd, (unsigned)e, span, m2);
      unsigned tr = (unsigned)mask_idx[iR], tc = (unsigned)mask_idx[iC];
      tval[k] = (tr << 16) | tc;
      atomicAdd(&cnt[tr / RPB], 1);
      atomicAdd(&cnt[tc / RPB], 1);
      int r = rows[e], c = cols[e];
      float v = 0.0f;
      if (alive[e]) {
        aval[k] = ((unsigned)r << 16) | (unsigned)c;
        atomicAdd(&cnt[(unsigned)r / RPB], 1);
        float xr = (float)deg[r] + 1e-12f;
        float xc = (float)deg[c] + 1e-12f;
        float dr = (float)(1.0 / sqrt((double)xr));
        float dc = (float)(1.0 / sqrt((double)xc));
        v = dr * dc;
      } else aval[k] = NOPE;
      out[e] = (float)r;
      out[E + e] = (float)c;
      out[2 * E + e] = v;
    } else { tval[k] = NOPE; aval[k] = NOPE; }
  }
  for (int i = i0 + tid; i < i1; i += APPT) atomicAdd(&cnt[i / RPB], 1);
  __syncthreads();
  // exclusive scan of cnt[1024] by wave 0 -> ofs (ushort)
  if (wid == 0) {
    int carry = 0;
    for (int c8 = 0; c8 < NB / 64; c8++) {
      int v = cnt[c8 * 64 + lane];
      int x = v;
      for (int d = 1; d < 64; d <<= 1) {
        int y = __shfl_up(x, d, 64);
        if (lane >= d) x += y;
      }
      ofs[c8 * 64 + lane] = (unsigned short)(carry + x - v);
      carry += __shfl(x, 63, 64);
    }
    if (lane == 0) ntot_s = carry;
  }
  __syncthreads();
  for (int i = tid; i < NB; i += APPT) cnt[i] = ofs[i];
  __syncthreads();
  // pass B: scatter from registers (+ self)
#pragma unroll
  for (int k = 0; k < NE; k++) {
    unsigned v = tval[k];
    if (v != NOPE) {
      unsigned tr = v >> 16, tc = v & 0xFFFFu;
      int p1 = atomicAdd(&cnt[tr / RPB], 1);
      sorted[p1] = v;
      int p2 = atomicAdd(&cnt[tc / RPB], 1);
      sorted[p2] = (tc << 16) | tr;
      unsigned a = aval[k];
      if (a != NOPE) {
        int p3 = atomicAdd(&cnt[(a >> 16) / RPB], 1);
        sorted[p3] = a;
      }
    }
  }
  for (int i = i0 + tid; i < i1; i += APPT) {
    int p = atomicAdd(&cnt[i / RPB], 1);
    sorted[p] = ((unsigned)i << 16) | (unsigned)i;
  }
  __syncthreads();
  // reserve global space: one atomicAdd per bucket per block
  int ntot = ntot_s;
  for (int b = tid; b < NB; b += APPT) {
    int end = (b < NB - 1) ? (int)ofs[b + 1] : ntot;
    int len = end - (int)ofs[b];
    cnt[b] = len ? atomicAdd(&cursors[b * CURSTRIDE], len) : 0;
  }
  __syncthreads();
  // coalesced flush (store local row id in high 16)
  for (int j = tid; j < ntot; j += APPT) {
    unsigned item = sorted[j];
    unsigned r = item >> 16;
    unsigned b = r / RPB;
    unsigned lr = r - b * RPB;
    int idx = cnt[b] + (j - (int)ofs[b]);
    if (idx < CAP) bucketmem[b * CAP + idx] = (lr << 16) | (item & 0xFFFFu);
  }
}

// ---------------- dedup: wave-per-row + summary bitmap (r18 form) ----------
__global__ __launch_bounds__(256) void k_dedup(unsigned *bucketmem,
                                               const int *cursors, int *uniq_cnt) {
  int b = blockIdx.x;
  int rowbase = b * RPB;
  if (rowbase >= NN) { if (threadIdx.x == 0) uniq_cnt[b] = 0; return; }

  __shared__ unsigned short arr[CAP];  // 16 KB
  __shared__ int cnt[RPB];
  __shared__ int rowend[RPB];
  __shared__ int curs[RPB];
  __shared__ int rowoff[RPB];
  __shared__ unsigned bm[4][WORDS];    // 20 KB wave-private bitmaps
  __shared__ unsigned sm[4][SWORDS];

  int tid = threadIdx.x, lane = tid & 63, wid = tid >> 6;
  int n = cursors[b * CURSTRIDE]; if (n > CAP) n = CAP;
  const unsigned *src = bucketmem + (size_t)b * CAP;

  for (int i = tid; i < RPB; i += 256) cnt[i] = 0;
  __syncthreads();
  for (int j = tid; j < n; j += 256) atomicAdd(&cnt[src[j] >> 16], 1);
  __syncthreads();
  // wave0 parallel exclusive scan over RPB rows
  if (wid == 0) {
    int v = (lane < RPB) ? cnt[lane] : 0;
    int x = v;
    for (int d = 1; d < 64; d <<= 1) {
      int y = __shfl_up(x, d, 64);
      if (lane >= d) x += y;
    }
    if (lane < RPB) { curs[lane] = x - v; rowend[lane] = x; }
  }
  __syncthreads();
  for (int j = tid; j < n; j += 256) {
    unsigned v = src[j];
    int p = atomicAdd(&curs[v >> 16], 1);
    arr[p] = (unsigned short)v;
  }
  for (int w = lane; w < WORDS; w += 64) bm[wid][w] = 0u;
  if (lane < SWORDS) sm[wid][lane] = 0u;
  __syncthreads();

  for (int r = wid; r < RPB; r += 4) {
    int s1 = rowend[r], s0 = s1 - cnt[r];
    for (int j = s0 + lane; j < s1; j += 64) {
      unsigned c = arr[j];
      atomicOr(&bm[wid][c >> 5], 1u << (c & 31));
      atomicOr(&sm[wid][c >> 10], 1u << ((c >> 5) & 31));
    }
    unsigned s = (lane < SWORDS) ? sm[wid][lane] : 0u;
    int m = 0;
    unsigned t = s;
    while (t) {
      int w = (lane << 5) + (__ffs(t) - 1);
      t &= t - 1;
      m += __popc(bm[wid][w]);
    }
    int x = m;
    for (int d = 1; d < 64; d <<= 1) {
      int y = __shfl_up(x, d, 64);
      if (lane >= d) x += y;
    }
    int u = __shfl(x, 63, 64);
    int pos = s0 + (x - m);
    t = s;
    while (t) {
      int w = (lane << 5) + (__ffs(t) - 1);
      t &= t - 1;
      unsigned mm = bm[wid][w];
      bm[wid][w] = 0u;
      while (mm) {
        int bit = __ffs(mm) - 1;
        mm &= mm - 1;
        arr[pos++] = (unsigned short)((w << 5) + bit);
      }
    }
    if (lane < SWORDS) sm[wid][lane] = 0u;
    if (lane == 0) cnt[r] = u;
  }
  __syncthreads();
  // wave0 parallel exclusive scan of unique counts
  if (wid == 0) {
    int v = (lane < RPB) ? cnt[lane] : 0;
    int x = v;
    for (int d = 1; d < 64; d <<= 1) {
      int y = __shfl_up(x, d, 64);
      if (lane >= d) x += y;
    }
    if (lane < RPB) rowoff[lane] = x - v;
    if (lane == RPB - 1) uniq_cnt[b] = x;
  }
  __syncthreads();
  // write uniques as packed (row<<16)|col — ascending == hash order
  unsigned *dst = bucketmem + (size_t)b * CAP;
  for (int r = wid; r < RPB; r += 4) {
    int s0 = r ? rowend[r - 1] : 0;
    int u = cnt[r], o = rowoff[r];
    unsigned rowpack = (unsigned)(rowbase + r) << 16;
    for (int j = lane; j < u; j += 64)
      dst[o + j] = rowpack | (unsigned)arr[s0 + j];
  }
}

// ---------------- emit (fused offset-reduction + diag) ----------------
__global__ __launch_bounds__(256) void k_emit(const unsigned *bucketmem,
                                              const int *uniq_cnt, float *out,
                                              int E, int U) {
  __shared__ int part[4];
  int b = blockIdx.x;
  int tid = threadIdx.x, lane = tid & 63, wid = tid >> 6;
  // ob = sum of uniq_cnt[0..b) via masked butterfly reduction
  int acc = 0;
  for (int i = tid; i < NB; i += 256)
    if (i < b) acc += uniq_cnt[i];
  for (int d = 1; d < 64; d <<= 1) acc += __shfl_xor(acc, d, 64);
  if (lane == 0) part[wid] = acc;
  __syncthreads();
  int ob = part[0] + part[1] + part[2] + part[3];
  int ub = uniq_cnt[b];
  const unsigned *src = bucketmem + (size_t)b * CAP;
  int base3 = 3 * E;
  for (int j = tid; j < ub; j += 256) {
    unsigned h = src[j];
    unsigned r = h >> 16;
    unsigned c = h & 0xFFFFu;
    int idx = ob + j;
    if (idx < U) {
      out[base3 + idx] = (float)r;
      out[base3 + U + idx] = (float)c;
      out[base3 + 2 * U + idx] = 1.0f;
    }
  }
  if (b == NB - 1 && tid == 0) {
    int C = ob + ub;
    if (C != U) {
      int d = C - U; if (d < 0) d = -d; if (d > 60000) d = 60000;
      out[base3] = (float)(300000 + d); // sentinel (should never fire)
    }
  }
}

// ---------------- launch ----------------
extern "C" void kernel_launch(void *const *d_in, const int *in_sizes, int n_in,
                              void *d_out, int out_size, void *d_ws,
                              size_t ws_size, hipStream_t stream) {
  const int *rows = (const int *)d_in[0];
  const int *cols = (const int *)d_in[1];
  const int *seeds = (const int *)d_in[3];
  const int E = in_sizes[0];
  const int ns = in_sizes[3];
  float *out = (float *)d_out;
  const int U = (out_size - 3 * E) / 3;

  // ---- workspace carve ----
  int *I = (int *)d_ws;
  int *deg = I;      I += NN;               // zeroed in k_level0
  int *cursors = I;  I += NB * CURSTRIDE;   // zeroed in k_level0
  int *uniq_cnt = I; I += NB;               // fully written by k_dedup
  unsigned char *cur = (unsigned char *)I;  // 3*NN bytes zeroed by k_zero16
  unsigned char *touched = cur + NN;
  unsigned char *mask_bfs = touched + NN;
  size_t zero_bytes = (size_t)(3 * NN);     // cur+touched+mask_bfs only
  int *J = (int *)(mask_bfs + NN);
  int *tem_num = J;  J += 1;
  J += 1; // pad to 8B
  int *mask_part = J; J += 40;              // popcount partials (fully written)
  unsigned short *mask_idx = (unsigned short *)J;
  J += NN / 2; // 40000 ushorts = 20000 ints
  unsigned *bucketmem = (unsigned *)J; J += (size_t)NB * CAP; // 32 MB
  unsigned char *alive = (unsigned char *)J; // E bytes (fully written)

  // ---- host key derivation (v0): key(1)=(0,1); split(3); randint split(2) ----
  unsigned F[3][2];
  tf2x32(0u, 1u, 0u, 0u, F[0][0], F[0][1]); // kS
  tf2x32(0u, 1u, 0u, 1u, F[1][0], F[1][1]); // kR
  tf2x32(0u, 1u, 0u, 2u, F[2][0], F[2][1]); // kC
  unsigned K[3][4];
  for (int s = 0; s < 3; s++) {
    tf2x32(F[s][0], F[s][1], 0u, 0u, K[s][0], K[s][1]); // k1 (higher bits)
    tf2x32(F[s][0], F[s][1], 0u, 1u, K[s][2], K[s][3]); // k2 (lower bits)
  }

  dim3 b(256);
  int gE = (E + 255) / 256;
  int gSS = (SAMPN + 255) / 256; // covers ns=2000 too
  int gT = (E + EPB - 1) / EPB;  // 228; also covers self nodes (228*176>=NN)
  int n16 = (int)(zero_bytes / 16);

  k_zero16<<<(n16 + 255) / 256, b, 0, stream>>>((uint4 *)cur, n16);
  k_seed_samp<<<gSS, b, 0, stream>>>(seeds, ns, cur, mask_bfs,
                                     K[0][0], K[0][1], K[0][2], K[0][3]);
  k_level0<<<gE, b, 0, stream>>>(rows, cols, E, cur, alive, touched, mask_bfs,
                                 deg, cursors);
  k_level1_deg<<<gE, b, 0, stream>>>(rows, cols, E, touched, alive, deg,
                                     (const unsigned *)mask_bfs, mask_part);
  k_mask_extract<<<40, b, 0, stream>>>((const unsigned *)mask_bfs, mask_part,
                                       mask_idx, tem_num);
  k_append<<<gT, dim3(APPT), 0, stream>>>(rows, cols, alive, deg, mask_idx,
                                          tem_num, cursors, bucketmem, out,
                                          K[1][0], K[1][1], K[1][2], K[1][3],
                                          K[2][0], K[2][1], K[2][2], K[2][3], E);
  k_dedup<<<NB, b, 0, stream>>>(bucketmem, cursors, uniq_cnt);
  k_emit<<<NB, b, 0, stream>>>(bucketmem, uniq_cnt, out, E, U);
}

// Round 11
// 252.052 us; speedup vs baseline: 1.2652x; 1.0004x over previous
//
#include <hip/hip_runtime.h>
#include <stdint.h>

// RandomMaskSubgraphs — round 24 (FINAL): lock in the measured champion (r18,
// 250.5us), the best of 11 tested configurations.
// Plateau analysis (10 rounds of on-chip evidence):
//  - k_append ~55us: VALU-issue 24us invariant; latency-bound. Block geometry
//    exhausted both directions (256thr: 2.5x worse r14; 1024thr: neutral r23).
//  - k_dedup ~48us: redesigns 0/4 (r15 scans neutral, r19 2-bucket neutral,
//    r21 col-partition -65%, r22 per-wave ctrs -1%). This form is its floor.
//  - Fusion: intra-kernel grid rendezvous costs ~50us MORE than a kernel
//    boundary (r16) — bucketmem round trip can't be removed profitably.
//  - fillBufferAligned (harness, 361MB @85% BW) not controllable.
//  All stages <20% HBM, <45% VALU: a sum of latency floors, not a pipe bound.
// Config: NB=1024/RPB=40/CAP=8192/CURSTRIDE=4; k_append APPT=512/EPB=5632/
// NE=11/455 blocks/68KB LDS; dedup wave-per-row bitmaps + wave0 shfl scans;
// mask pipeline split (popcount in level1, 40-block extract).
// PRNG v0 (partitionable split + randint subkey split) bit-exact since r4.

#define NN 40000
#define SAMPN (NN / 2)
#define WORDS 1250               // col bitmap words (40000/32)
#define SWORDS 40                // summary words
#define NB 1024                  // buckets (append bins == dedup blocks)
#define RPB 40                   // rows per bucket (1024*40 >= 40000)
#define CAP 8192                 // entries per bucket (mean ~5.3k)
#define CURSTRIDE 4
#define APPT 512                 // k_append threads per block
#define EPB 5632                 // edges per append block (11*512)
#define NE (EPB / APPT)          // 11 edges per thread
#define SELFPB 88                // self nodes per append block (455*88 >= 40000)
#define SCAP (3 * EPB + SELFPB)  // 16984 -> 67.9 KB
#define MWPB 250                 // mask words per extract block (40*250=10000)

// ---------------- Threefry-2x32 (20 rounds, JAX schedule) ----------------
__host__ __device__ __forceinline__ void tf2x32(unsigned k0, unsigned k1,
                                                unsigned x0, unsigned x1,
                                                unsigned &o0, unsigned &o1) {
  unsigned ks2 = k0 ^ k1 ^ 0x1BD11BDAu;
  x0 += k0; x1 += k1;
#define TFR(r) { x0 += x1; x1 = (x1 << (r)) | (x1 >> (32 - (r))); x1 ^= x0; }
  TFR(13) TFR(15) TFR(26) TFR(6)
  x0 += k1;  x1 += ks2 + 1u;
  TFR(17) TFR(29) TFR(16) TFR(24)
  x0 += ks2; x1 += k0 + 2u;
  TFR(13) TFR(15) TFR(26) TFR(6)
  x0 += k0;  x1 += k1 + 3u;
  TFR(17) TFR(29) TFR(16) TFR(24)
  x0 += k1;  x1 += ks2 + 4u;
  TFR(13) TFR(15) TFR(26) TFR(6)
  x0 += ks2; x1 += k0 + 5u;
#undef TFR
  o0 = x0; o1 = x1;
}

// jax.random.randint element e with pre-split subkeys k1=(a,b), k2=(c,d).
// m2 = ((65536 % span)^2) % span, precomputed by the caller (span-invariant).
__device__ __forceinline__ unsigned jrand(unsigned a, unsigned b, unsigned c,
                                          unsigned d, unsigned e, unsigned span,
                                          unsigned m2) {
  unsigned x0, x1, y0, y1;
  tf2x32(a, b, 0u, e, x0, x1);
  unsigned hi = x0 ^ x1;
  tf2x32(c, d, 0u, e, y0, y1);
  unsigned lo = y0 ^ y1;
  return ((hi % span) * m2 + (lo % span)) % span;
}

// ---------------- init / BFS ----------------
__global__ void k_zero16(uint4 *p, int n16) {
  int i = blockIdx.x * blockDim.x + threadIdx.x;
  if (i < n16) p[i] = make_uint4(0u, 0u, 0u, 0u);
}
__global__ void k_seed_samp(const int *seeds, int ns, unsigned char *cur,
                            unsigned char *mask_bfs,
                            unsigned a, unsigned b, unsigned c, unsigned d) {
  int i = blockIdx.x * blockDim.x + threadIdx.x;
  if (i < ns) { int s = seeds[i]; cur[s] = 1; mask_bfs[s] = 1; }
  if (i < SAMPN) {
    constexpr unsigned M2 =
        ((65536u % (unsigned)NN) * (65536u % (unsigned)NN)) % (unsigned)NN;
    unsigned idx = jrand(a, b, c, d, (unsigned)i, (unsigned)NN, M2);
    mask_bfs[idx] = 1;
  }
}
// level-0 BFS; also zeroes deg + cursors (used by later kernels only).
__global__ void k_level0(const int *rows, const int *cols, int E,
                         const unsigned char *cur, unsigned char *alive,
                         unsigned char *touched, unsigned char *mask_bfs,
                         int *deg, int *cursors) {
  int e = blockIdx.x * blockDim.x + threadIdx.x;
  if (e < NN) deg[e] = 0;
  int e2 = e - NN;
  if (e2 >= 0 && e2 < NB * CURSTRIDE) cursors[e2] = 0;
  if (e >= E) return;
  int r = rows[e], c = cols[e];
  if (cur[r] | cur[c]) {
    alive[e] = 0;
    touched[r] = 1; touched[c] = 1;
    mask_bfs[r] = 1; mask_bfs[c] = 1;
  } else alive[e] = 1;
}
// level-1 BFS + degree; blocks 0..39 also compute mask popcount partials
// (mask_bfs is complete before this kernel launches).
__global__ void k_level1_deg(const int *rows, const int *cols, int E,
                             const unsigned char *touched, unsigned char *alive,
                             int *deg, const unsigned *maskw, int *mask_part) {
  int tid = threadIdx.x;
  int e = blockIdx.x * blockDim.x + tid;
  if (e < E && alive[e]) {
    int r = rows[e];
    if (touched[r] | touched[cols[e]]) alive[e] = 0;
    else atomicAdd(&deg[r], 1);
  }
  if (blockIdx.x < 40) {
    __shared__ int red[4];
    int lane = tid & 63, wid = tid >> 6;
    int c = (tid < MWPB) ? __popc(maskw[blockIdx.x * MWPB + tid]) : 0;
    for (int d = 1; d < 64; d <<= 1) c += __shfl_xor(c, d, 64);
    if (lane == 0) red[wid] = c;
    __syncthreads();
    if (tid == 0) mask_part[blockIdx.x] = red[0] + red[1] + red[2] + red[3];
  }
}

// ---------------- mask extraction (40 blocks; replaces 1-block scan) --------
__global__ __launch_bounds__(256) void k_mask_extract(const unsigned *f,
                                                      const int *mask_part,
                                                      unsigned short *mask_idx,
                                                      int *tem_num) {
  __shared__ int wsum[4];
  __shared__ int basech;
  int b = blockIdx.x, tid = threadIdx.x, lane = tid & 63, wid = tid >> 6;
  if (wid == 0) {
    int v = (lane < 40) ? mask_part[lane] : 0;
    int x = v;
    for (int d = 1; d < 64; d <<= 1) {
      int y = __shfl_up(x, d, 64);
      if (lane >= d) x += y;
    }
    int basev = __shfl(x - v, b, 64);   // exclusive prefix at own block
    int total = __shfl(x, 39, 64);
    if (lane == 0) {
      basech = basev;
      if (b == 0) *tem_num = total;
    }
  }
  int w = b * MWPB + tid;
  unsigned u = (tid < MWPB) ? f[w] : 0u;
  int c = __popc(u);
  int x = c;
  for (int d = 1; d < 64; d <<= 1) {
    int y = __shfl_up(x, d, 64);
    if (lane >= d) x += y;
  }
  if (lane == 63) wsum[wid] = x;
  __syncthreads();
  if (wid == 0) {
    int v = (lane < 4) ? wsum[lane] : 0;
    int y = v;
    for (int d = 1; d < 4; d <<= 1) {
      int z = __shfl_up(y, d, 64);
      if (lane >= d) y += z;
    }
    if (lane < 4) wsum[lane] = y - v;
  }
  __syncthreads();
  int off = basech + wsum[wid] + (x - c);
  while (u) {
    int byte = (__ffs(u) - 1) >> 3;
    u &= u - 1;
    mask_idx[off++] = (unsigned short)(w * 4 + byte);
  }
}

// ---------------- binned append (tem + alive + self) + fused encoder ----------
__global__ __launch_bounds__(APPT) void k_append(
    const int *rows, const int *cols, const unsigned char *alive,
    const int *deg, const unsigned short *mask_idx, const int *tem_num,
    int *cursors, unsigned *bucketmem, float *out,
    unsigned ra, unsigned rb, unsigned rc, unsigned rd,
    unsigned ca, unsigned cb, unsigned cc, unsigned cd, int E) {
  __shared__ unsigned sorted[SCAP];     // 67.9 KB
  __shared__ int cnt[NB];               // 4 KB
  __shared__ unsigned short ofs[NB];    // 2 KB
  __shared__ int ntot_s;
  int tid = threadIdx.x, lane = tid & 63, wid = tid >> 6;
  int e0 = blockIdx.x * EPB;
  int i0 = blockIdx.x * SELFPB;         // self-node range
  int i1 = i0 + SELFPB; if (i1 > NN) i1 = NN;
  unsigned span = (unsigned)*tem_num;
  unsigned mtmp = 65536u % span;
  unsigned m2 = (mtmp * mtmp) % span;   // hoisted out of jrand (span-invariant)
  const unsigned NOPE = 0xFFFFFFFFu;

  unsigned tval[NE], aval[NE];

  for (int i = tid; i < NB; i += APPT) cnt[i] = 0;
  __syncthreads();
  // pass A: draw + gather once, count, cache in registers; fused encoder out
#pragma unroll
  for (int k = 0; k < NE; k++) {
    int e = e0 + k * APPT + tid;
    if (e < E) {
      unsigned iR = jrand(ra, rb, rc, rd, (unsigned)e, span, m2);
      unsigned iC = jrand(ca, cb, cc, cd, (unsigned)e, span, m2);
      unsigned tr = (unsigned)mask_idx[iR], tc = (unsigned)mask_idx[iC];
      tval[k] = (tr << 16) | tc;
      atomicAdd(&cnt[tr / RPB], 1);
      atomicAdd(&cnt[tc / RPB], 1);
      int r = rows[e], c = cols[e];
      float v = 0.0f;
      if (alive[e]) {
        aval[k] = ((unsigned)r << 16) | (unsigned)c;
        atomicAdd(&cnt[(unsigned)r / RPB], 1);
        float xr = (float)deg[r] + 1e-12f;
        float xc = (float)deg[c] + 1e-12f;
        float dr = (float)(1.0 / sqrt((double)xr));
        float dc = (float)(1.0 / sqrt((double)xc));
        v = dr * dc;
      } else aval[k] = NOPE;
      out[e] = (float)r;
      out[E + e] = (float)c;
      out[2 * E + e] = v;
    } else { tval[k] = NOPE; aval[k] = NOPE; }
  }
  for (int i = i0 + tid; i < i1; i += APPT) atomicAdd(&cnt[i / RPB], 1);
  __syncthreads();
  // exclusive scan of cnt[1024] by wave 0 -> ofs (ushort)
  if (wid == 0) {
    int carry = 0;
    for (int c8 = 0; c8 < NB / 64; c8++) {
      int v = cnt[c8 * 64 + lane];
      int x = v;
      for (int d = 1; d < 64; d <<= 1) {
        int y = __shfl_up(x, d, 64);
        if (lane >= d) x += y;
      }
      ofs[c8 * 64 + lane] = (unsigned short)(carry + x - v);
      carry += __shfl(x, 63, 64);
    }
    if (lane == 0) ntot_s = carry;
  }
  __syncthreads();
  for (int i = tid; i < NB; i += APPT) cnt[i] = ofs[i];
  __syncthreads();
  // pass B: scatter from registers (+ self)
#pragma unroll
  for (int k = 0; k < NE; k++) {
    unsigned v = tval[k];
    if (v != NOPE) {
      unsigned tr = v >> 16, tc = v & 0xFFFFu;
      int p1 = atomicAdd(&cnt[tr / RPB], 1);
      sorted[p1] = v;
      int p2 = atomicAdd(&cnt[tc / RPB], 1);
      sorted[p2] = (tc << 16) | tr;
      unsigned a = aval[k];
      if (a != NOPE) {
        int p3 = atomicAdd(&cnt[(a >> 16) / RPB], 1);
        sorted[p3] = a;
      }
    }
  }
  for (int i = i0 + tid; i < i1; i += APPT) {
    int p = atomicAdd(&cnt[i / RPB], 1);
    sorted[p] = ((unsigned)i << 16) | (unsigned)i;
  }
  __syncthreads();
  // reserve global space: one atomicAdd per bucket per block
  int ntot = ntot_s;
  for (int b = tid; b < NB; b += APPT) {
    int end = (b < NB - 1) ? (int)ofs[b + 1] : ntot;
    int len = end - (int)ofs[b];
    cnt[b] = len ? atomicAdd(&cursors[b * CURSTRIDE], len) : 0;
  }
  __syncthreads();
  // coalesced flush (store local row id in high 16)
  for (int j = tid; j < ntot; j += APPT) {
    unsigned item = sorted[j];
    unsigned r = item >> 16;
    unsigned b = r / RPB;
    unsigned lr = r - b * RPB;
    int idx = cnt[b] + (j - (int)ofs[b]);
    if (idx < CAP) bucketmem[b * CAP + idx] = (lr << 16) | (item & 0xFFFFu);
  }
}

// ---------------- dedup: wave-per-row + summary bitmap (single read) --------
__global__ __launch_bounds__(256) void k_dedup(unsigned *bucketmem,
                                               const int *cursors, int *uniq_cnt) {
  int b = blockIdx.x;
  int rowbase = b * RPB;
  if (rowbase >= NN) { if (threadIdx.x == 0) uniq_cnt[b] = 0; return; }

  __shared__ unsigned short arr[CAP];  // 16 KB
  __shared__ int cnt[RPB];
  __shared__ int rowend[RPB];
  __shared__ int curs[RPB];
  __shared__ int rowoff[RPB];
  __shared__ unsigned bm[4][WORDS];    // 20 KB wave-private bitmaps
  __shared__ unsigned sm[4][SWORDS];

  int tid = threadIdx.x, lane = tid & 63, wid = tid >> 6;
  int n = cursors[b * CURSTRIDE]; if (n > CAP) n = CAP;
  const unsigned *src = bucketmem + (size_t)b * CAP;

  for (int i = tid; i < RPB; i += 256) cnt[i] = 0;
  __syncthreads();
  for (int j = tid; j < n; j += 256) atomicAdd(&cnt[src[j] >> 16], 1);
  __syncthreads();
  // wave0 parallel exclusive scan over RPB rows
  if (wid == 0) {
    int v = (lane < RPB) ? cnt[lane] : 0;
    int x = v;
    for (int d = 1; d < 64; d <<= 1) {
      int y = __shfl_up(x, d, 64);
      if (lane >= d) x += y;
    }
    if (lane < RPB) { curs[lane] = x - v; rowend[lane] = x; }
  }
  __syncthreads();
  for (int j = tid; j < n; j += 256) {
    unsigned v = src[j];
    int p = atomicAdd(&curs[v >> 16], 1);
    arr[p] = (unsigned short)v;
  }
  for (int w = lane; w < WORDS; w += 64) bm[wid][w] = 0u;
  if (lane < SWORDS) sm[wid][lane] = 0u;
  __syncthreads();

  for (int r = wid; r < RPB; r += 4) {
    int s1 = rowend[r], s0 = s1 - cnt[r];
    for (int j = s0 + lane; j < s1; j += 64) {
      unsigned c = arr[j];
      atomicOr(&bm[wid][c >> 5], 1u << (c & 31));
      atomicOr(&sm[wid][c >> 10], 1u << ((c >> 5) & 31));
    }
    unsigned s = (lane < SWORDS) ? sm[wid][lane] : 0u;
    int m = 0;
    unsigned t = s;
    while (t) {
      int w = (lane << 5) + (__ffs(t) - 1);
      t &= t - 1;
      m += __popc(bm[wid][w]);
    }
    int x = m;
    for (int d = 1; d < 64; d <<= 1) {
      int y = __shfl_up(x, d, 64);
      if (lane >= d) x += y;
    }
    int u = __shfl(x, 63, 64);
    int pos = s0 + (x - m);
    t = s;
    while (t) {
      int w = (lane << 5) + (__ffs(t) - 1);
      t &= t - 1;
      unsigned mm = bm[wid][w];
      bm[wid][w] = 0u;
      while (mm) {
        int bit = __ffs(mm) - 1;
        mm &= mm - 1;
        arr[pos++] = (unsigned short)((w << 5) + bit);
      }
    }
    if (lane < SWORDS) sm[wid][lane] = 0u;
    if (lane == 0) cnt[r] = u;
  }
  __syncthreads();
  // wave0 parallel exclusive scan of unique counts
  if (wid == 0) {
    int v = (lane < RPB) ? cnt[lane] : 0;
    int x = v;
    for (int d = 1; d < 64; d <<= 1) {
      int y = __shfl_up(x, d, 64);
      if (lane >= d) x += y;
    }
    if (lane < RPB) rowoff[lane] = x - v;
    if (lane == RPB - 1) uniq_cnt[b] = x;
  }
  __syncthreads();
  // write uniques as packed (row<<16)|col — ascending == hash order
  unsigned *dst = bucketmem + (size_t)b * CAP;
  for (int r = wid; r < RPB; r += 4) {
    int s0 = r ? rowend[r - 1] : 0;
    int u = cnt[r], o = rowoff[r];
    unsigned rowpack = (unsigned)(rowbase + r) << 16;
    for (int j = lane; j < u; j += 64)
      dst[o + j] = rowpack | (unsigned)arr[s0 + j];
  }
}

// ---------------- emit (fused offset-reduction + diag) ----------------
__global__ __launch_bounds__(256) void k_emit(const unsigned *bucketmem,
                                              const int *uniq_cnt, float *out,
                                              int E, int U) {
  __shared__ int part[4];
  int b = blockIdx.x;
  int tid = threadIdx.x, lane = tid & 63, wid = tid >> 6;
  // ob = sum of uniq_cnt[0..b) via masked butterfly reduction
  int acc = 0;
  for (int i = tid; i < NB; i += 256)
    if (i < b) acc += uniq_cnt[i];
  for (int d = 1; d < 64; d <<= 1) acc += __shfl_xor(acc, d, 64);
  if (lane == 0) part[wid] = acc;
  __syncthreads();
  int ob = part[0] + part[1] + part[2] + part[3];
  int ub = uniq_cnt[b];
  const unsigned *src = bucketmem + (size_t)b * CAP;
  int base3 = 3 * E;
  for (int j = tid; j < ub; j += 256) {
    unsigned h = src[j];
    unsigned r = h >> 16;
    unsigned c = h & 0xFFFFu;
    int idx = ob + j;
    if (idx < U) {
      out[base3 + idx] = (float)r;
      out[base3 + U + idx] = (float)c;
      out[base3 + 2 * U + idx] = 1.0f;
    }
  }
  if (b == NB - 1 && tid == 0) {
    int C = ob + ub;
    if (C != U) {
      int d = C - U; if (d < 0) d = -d; if (d > 60000) d = 60000;
      out[base3] = (float)(300000 + d); // sentinel (should never fire)
    }
  }
}

// ---------------- launch ----------------
extern "C" void kernel_launch(void *const *d_in, const int *in_sizes, int n_in,
                              void *d_out, int out_size, void *d_ws,
                              size_t ws_size, hipStream_t stream) {
  const int *rows = (const int *)d_in[0];
  const int *cols = (const int *)d_in[1];
  const int *seeds = (const int *)d_in[3];
  const int E = in_sizes[0];
  const int ns = in_sizes[3];
  float *out = (float *)d_out;
  const int U = (out_size - 3 * E) / 3;

  // ---- workspace carve ----
  int *I = (int *)d_ws;
  int *deg = I;      I += NN;               // zeroed in k_level0
  int *cursors = I;  I += NB * CURSTRIDE;   // zeroed in k_level0
  int *uniq_cnt = I; I += NB;               // fully written by k_dedup
  unsigned char *cur = (unsigned char *)I;  // 3*NN bytes zeroed by k_zero16
  unsigned char *touched = cur + NN;
  unsigned char *mask_bfs = touched + NN;
  size_t zero_bytes = (size_t)(3 * NN);     // cur+touched+mask_bfs only
  int *J = (int *)(mask_bfs + NN);
  int *tem_num = J;  J += 1;
  J += 1; // pad to 8B
  int *mask_part = J; J += 40;              // popcount partials (fully written)
  unsigned short *mask_idx = (unsigned short *)J;
  J += NN / 2; // 40000 ushorts = 20000 ints
  unsigned *bucketmem = (unsigned *)J; J += (size_t)NB * CAP; // 32 MB
  unsigned char *alive = (unsigned char *)J; // E bytes (fully written)

  // ---- host key derivation (v0): key(1)=(0,1); split(3); randint split(2) ----
  unsigned F[3][2];
  tf2x32(0u, 1u, 0u, 0u, F[0][0], F[0][1]); // kS
  tf2x32(0u, 1u, 0u, 1u, F[1][0], F[1][1]); // kR
  tf2x32(0u, 1u, 0u, 2u, F[2][0], F[2][1]); // kC
  unsigned K[3][4];
  for (int s = 0; s < 3; s++) {
    tf2x32(F[s][0], F[s][1], 0u, 0u, K[s][0], K[s][1]); // k1 (higher bits)
    tf2x32(F[s][0], F[s][1], 0u, 1u, K[s][2], K[s][3]); // k2 (lower bits)
  }

  dim3 b(256);
  int gE = (E + 255) / 256;
  int gSS = (SAMPN + 255) / 256; // covers ns=2000 too
  int gT = (E + EPB - 1) / EPB;  // 455; also covers self nodes (455*88>=NN)
  int n16 = (int)(zero_bytes / 16);

  k_zero16<<<(n16 + 255) / 256, b, 0, stream>>>((uint4 *)cur, n16);
  k_seed_samp<<<gSS, b, 0, stream>>>(seeds, ns, cur, mask_bfs,
                                     K[0][0], K[0][1], K[0][2], K[0][3]);
  k_level0<<<gE, b, 0, stream>>>(rows, cols, E, cur, alive, touched, mask_bfs,
                                 deg, cursors);
  k_level1_deg<<<gE, b, 0, stream>>>(rows, cols, E, touched, alive, deg,
                                     (const unsigned *)mask_bfs, mask_part);
  k_mask_extract<<<40, b, 0, stream>>>((const unsigned *)mask_bfs, mask_part,
                                       mask_idx, tem_num);
  k_append<<<gT, dim3(APPT), 0, stream>>>(rows, cols, alive, deg, mask_idx,
                                          tem_num, cursors, bucketmem, out,
                                          K[1][0], K[1][1], K[1][2], K[1][3],
                                          K[2][0], K[2][1], K[2][2], K[2][3], E);
  k_dedup<<<NB, b, 0, stream>>>(bucketmem, cursors, uniq_cnt);
  k_emit<<<NB, b, 0, stream>>>(bucketmem, uniq_cnt, out, E, U);
}